// Round 10
// baseline (525.550 us; speedup 1.0000x reference)
//
#include <hip/hip_runtime.h>
#include <math.h>

// ---------------------------------------------------------------------------
// SPA graph conv, 2 layers. N=50000, E=800000, C=128, OUT=64, HS=16, K=4.
// R9b: R9 with fp8-decode fixed (byte-select must be a literal constant ->
//     fp8x4 helper). 2-edges-per-wave-load gathers with FULL-WAVE node
//     ownership: fp8 stats row = 128B = 32 lanes x uint; bf16 agg row =
//     256B = 32 x uint2. Half-wave h = lane>>5 picks the edge of the pair;
//     lane owns 4 channels. csr/alpha staged in per-wave LDS (broadcast
//     ds_read). Halves combined once per node via shfl_xor(32).
// ---------------------------------------------------------------------------

__device__ __forceinline__ float wave_max(float v) {
#pragma unroll
  for (int o = 32; o; o >>= 1) v = fmaxf(v, __shfl_xor(v, o, 64));
  return v;
}
__device__ __forceinline__ float wave_sum(float v) {
#pragma unroll
  for (int o = 32; o; o >>= 1) v += __shfl_xor(v, o, 64);
  return v;
}

// bf16 pair packed in a uint: low ushort = even channel, high = odd channel.
__device__ __forceinline__ float bflo(unsigned u) {
  return __uint_as_float(u << 16);
}
__device__ __forceinline__ float bfhi(unsigned u) {
  return __uint_as_float(u & 0xffff0000u);
}
__device__ __forceinline__ unsigned f2bf(float f) {  // RNE
  unsigned x = __float_as_uint(f);
  return (x + 0x7fffu + ((x >> 16) & 1u)) >> 16;
}
__device__ __forceinline__ unsigned packbf(float a, float b) {
  return f2bf(a) | (f2bf(b) << 16);
}

// fp8 e4m3: decode 4 bytes of a uint with LITERAL byte selectors.
__device__ __forceinline__ void fp8x4(unsigned u, float r[4]) {
  r[0] = __builtin_amdgcn_cvt_f32_fp8(u, 0);
  r[1] = __builtin_amdgcn_cvt_f32_fp8(u, 1);
  r[2] = __builtin_amdgcn_cvt_f32_fp8(u, 2);
  r[3] = __builtin_amdgcn_cvt_f32_fp8(u, 3);
}

// ---------------------------------------------------------------------------
// GEMM: Y[r][c] = sum_k X[r][k]*W[c][k] + bias[c].  K fixed = 128.
// BFOUT: also write bf16 shadow (uint = 2ch) and fp8 shadow (byte = 1ch).
// ---------------------------------------------------------------------------
template <int COLS, bool BFOUT>
__global__ __launch_bounds__(256) void gemm_bias(
    const float* __restrict__ X, const float* __restrict__ W,
    const float* __restrict__ bias, float* __restrict__ Y,
    unsigned* __restrict__ Yb, unsigned char* __restrict__ Y8, int nrows) {
  __shared__ float Wt[128 * COLS];
  const int t = threadIdx.x;
  for (int q = t; q < COLS * 32; q += 256) {
    const int c = q >> 5;
    const int k0 = (q & 31) << 2;
    const float4 w = *(const float4*)(W + c * 128 + k0);
    Wt[(k0 + 0) * COLS + c] = w.x;
    Wt[(k0 + 1) * COLS + c] = w.y;
    Wt[(k0 + 2) * COLS + c] = w.z;
    Wt[(k0 + 3) * COLS + c] = w.w;
  }
  __syncthreads();
  const int tx = t & 15, ty = t >> 4;
  const long rbase = (long)blockIdx.x * 128 + ty * 8;
  constexpr int NG = COLS / 64;
  float acc[8][NG * 4];
#pragma unroll
  for (int i = 0; i < 8; i++)
#pragma unroll
    for (int j = 0; j < NG * 4; j++) acc[i][j] = 0.0f;
  const float* xp[8];
#pragma unroll
  for (int i = 0; i < 8; i++) {
    long r = rbase + i;
    if (r > nrows - 1) r = nrows - 1;
    xp[i] = X + r * 128;
  }
  for (int k0 = 0; k0 < 128; k0 += 4) {
    float4 xv[8];
#pragma unroll
    for (int i = 0; i < 8; i++) xv[i] = *(const float4*)(xp[i] + k0);
#pragma unroll
    for (int kk = 0; kk < 4; kk++) {
      float4 wv[NG];
#pragma unroll
      for (int g = 0; g < NG; g++)
        wv[g] = *(const float4*)(&Wt[(k0 + kk) * COLS + g * 64 + 4 * tx]);
#pragma unroll
      for (int i = 0; i < 8; i++) {
        const float xs = ((const float*)&xv[i])[kk];
#pragma unroll
        for (int g = 0; g < NG; g++) {
          acc[i][g * 4 + 0] = fmaf(xs, wv[g].x, acc[i][g * 4 + 0]);
          acc[i][g * 4 + 1] = fmaf(xs, wv[g].y, acc[i][g * 4 + 1]);
          acc[i][g * 4 + 2] = fmaf(xs, wv[g].z, acc[i][g * 4 + 2]);
          acc[i][g * 4 + 3] = fmaf(xs, wv[g].w, acc[i][g * 4 + 3]);
        }
      }
    }
  }
  float4 bv[NG];
#pragma unroll
  for (int g = 0; g < NG; g++) bv[g] = *(const float4*)(bias + g * 64 + 4 * tx);
#pragma unroll
  for (int i = 0; i < 8; i++) {
    const long r = rbase + i;
    if (r < nrows) {
#pragma unroll
      for (int g = 0; g < NG; g++) {
        float4 o;
        o.x = acc[i][g * 4 + 0] + bv[g].x;
        o.y = acc[i][g * 4 + 1] + bv[g].y;
        o.z = acc[i][g * 4 + 2] + bv[g].z;
        o.w = acc[i][g * 4 + 3] + bv[g].w;
        const int c = g * 64 + 4 * tx;
        *(float4*)(Y + r * COLS + c) = o;
        if (BFOUT) {
          uint2 p;
          p.x = packbf(o.x, o.y);
          p.y = packbf(o.z, o.w);
          *(uint2*)(Yb + r * (COLS / 2) + (c >> 1)) = p;
          unsigned w8 = __builtin_amdgcn_cvt_pk_fp8_f32(o.x, o.y, 0, false);
          w8 = __builtin_amdgcn_cvt_pk_fp8_f32(o.z, o.w, w8, true);
          ((unsigned*)(Y8 + (long)r * COLS))[c >> 2] = w8;
        }
      }
    }
  }
}

// ---------------------------------------------------------------------------
// Edge moment stats, fp8 gather, 2 edges per wave-load.
// Wave owns node i. h = lane>>5 selects the edge of each pair; lane owns
// channels 4j..4j+3 (j = lane&31, uint = 4 fp8). csr staged in LDS,
// broadcast ds_read in the loop. Halves combined via shfl_xor(32).
// ---------------------------------------------------------------------------
__global__ __launch_bounds__(256) void edge_stats_f8(
    const unsigned char* __restrict__ X8, const int* __restrict__ csr,
    const int* __restrict__ offs, int n, float* __restrict__ stat) {
  __shared__ float pS[4][128];
  __shared__ float pQ[4][128];
  __shared__ int sidx[4][128];
  const unsigned* __restrict__ X32 = (const unsigned*)X8;
  const int t = threadIdx.x;
  const int w = t >> 6, l = t & 63;
  const int h = l >> 5, j = l & 31;
  const int wid = blockIdx.x * 4 + w;
  const int nw = gridDim.x * 4;
  float ss[4] = {0.f, 0.f, 0.f, 0.f};
  float qq[4] = {0.f, 0.f, 0.f, 0.f};
  for (int i = wid; i < n; i += nw) {
    const int beg = offs[i], end = offs[i + 1];
    const int deg = end - beg;
    const unsigned ud = X32[(long)i * 32 + j];
    float xd[4];
    fp8x4(ud, xd);
    if (deg <= 128) {
      if (l < deg) sidx[w][l] = csr[beg + l];
      if (64 + l < deg) sidx[w][64 + l] = csr[beg + 64 + l];
      int b = 0;
      for (; b + 8 <= deg; b += 8) {
        int sx[4];
#pragma unroll
        for (int u = 0; u < 4; u++) sx[u] = sidx[w][b + 2 * u + h];
        unsigned ua[4];
#pragma unroll
        for (int u = 0; u < 4; u++) ua[u] = X32[(long)sx[u] * 32 + j];
#pragma unroll
        for (int u = 0; u < 4; u++) {
          float xa[4];
          fp8x4(ua[u], xa);
#pragma unroll
          for (int c = 0; c < 4; c++) {
            const float d = xa[c] - xd[c];
            const float d2 = d * d;
            ss[c] += d2;
            qq[c] = fmaf(d2, d2, qq[c]);
          }
        }
      }
      for (; b + 2 <= deg; b += 2) {
        const int sx = sidx[w][b + h];
        const unsigned ua = X32[(long)sx * 32 + j];
        float xa[4];
        fp8x4(ua, xa);
#pragma unroll
        for (int c = 0; c < 4; c++) {
          const float d = xa[c] - xd[c];
          const float d2 = d * d;
          ss[c] += d2;
          qq[c] = fmaf(d2, d2, qq[c]);
        }
      }
      if (b < deg && h == 0) {  // odd remainder edge: half 0 only
        const int sx = sidx[w][b];
        const unsigned ua = X32[(long)sx * 32 + j];
        float xa[4];
        fp8x4(ua, xa);
#pragma unroll
        for (int c = 0; c < 4; c++) {
          const float d = xa[c] - xd[c];
          const float d2 = d * d;
          ss[c] += d2;
          qq[c] = fmaf(d2, d2, qq[c]);
        }
      }
    } else {
      // fallback: halves alternate edges
      for (int p = beg + h; p < end; p += 2) {
        const int sx = csr[p];
        const unsigned ua = X32[(long)sx * 32 + j];
        float xa[4];
        fp8x4(ua, xa);
#pragma unroll
        for (int c = 0; c < 4; c++) {
          const float d = xa[c] - xd[c];
          const float d2 = d * d;
          ss[c] += d2;
          qq[c] = fmaf(d2, d2, qq[c]);
        }
      }
    }
  }
#pragma unroll
  for (int c = 0; c < 4; c++) {
    ss[c] += __shfl_xor(ss[c], 32, 64);
    qq[c] += __shfl_xor(qq[c], 32, 64);
  }
  if (l < 32) {
#pragma unroll
    for (int c = 0; c < 4; c++) {
      pS[w][4 * j + c] = ss[c];
      pQ[w][4 * j + c] = qq[c];
    }
  }
  __syncthreads();
  if (t < 128) {
    atomicAdd(&stat[t], pS[0][t] + pS[1][t] + pS[2][t] + pS[3][t]);
  } else {
    const int c = t - 128;
    atomicAdd(&stat[128 + c], pQ[0][c] + pQ[1][c] + pQ[2][c] + pQ[3][c]);
  }
}

// ---------------------------------------------------------------------------
// node_scores with fused att computation: every block recomputes the att
// vectors from stat (tiny, deterministic), then streams per-node dots.
// ---------------------------------------------------------------------------
__global__ __launch_bounds__(256) void node_scores_att(
    const float* __restrict__ X, const float* __restrict__ stat,
    const float* __restrict__ src_w, const float* __restrict__ src_b,
    const float* __restrict__ dst_w, const float* __restrict__ dst_b,
    const float* __restrict__ tq, float* __restrict__ a_src,
    float* __restrict__ a_dst, int n, float Ef) {
  __shared__ float red[4][128];
  __shared__ float attL[128];
  __shared__ float attR[128];
  const int t = threadIdx.x;
  float S[4];
  if (t < 128) {
    const int c = t;
    const float sum = stat[c], sq = stat[128 + c];
    const float m1 = sum / Ef;
    float var = (sq - sum * (sum / Ef)) / (Ef - 1.0f);
    var = fmaxf(var, 0.0f);
    const float sd = sqrtf(var);
    const float m2 = sd + 1e-5f;
    S[0] = m1;
    S[1] = sd;
    S[2] = (m1 * m1 * m1) / (m2 * m2 * m2);
    const float m12 = m1 * m1, m22 = m2 * m2;
    S[3] = (m12 * m12) / (m22 * m22);
#pragma unroll
    for (int jj = 0; jj < 4; jj++) {
      if (isnan(S[jj])) S[jj] = 0.0f;
      S[jj] = tanhf(S[jj]);
      red[jj][c] = S[jj] * S[jj];
    }
  }
  for (int o = 64; o; o >>= 1) {
    __syncthreads();
    if (t < o) {
#pragma unroll
      for (int jj = 0; jj < 4; jj++) red[jj][t] += red[jj][t + o];
    }
  }
  __syncthreads();
  if (t < 128) {
#pragma unroll
    for (int jj = 0; jj < 4; jj++) S[jj] /= fmaxf(sqrtf(red[jj][0]), 1e-12f);
    float al = 0.0f, ar = 0.0f;
#pragma unroll
    for (int jj = 0; jj < 16; jj++) {
      float tl = src_b[jj], tr = dst_b[jj];
#pragma unroll
      for (int k = 0; k < 4; k++) {
        tl += S[k] * src_w[jj * 4 + k];
        tr += S[k] * dst_w[jj * 4 + k];
      }
      al += tq[jj] * tl;
      ar += tq[jj] * tr;
    }
    attL[t] = al;
    attR[t] = ar;
  }
  __syncthreads();
  const int l = t & 63;
  const float2 al2 = make_float2(attL[2 * l], attL[2 * l + 1]);
  const float2 ar2 = make_float2(attR[2 * l], attR[2 * l + 1]);
  const int wid = blockIdx.x * 4 + (t >> 6);
  const int nw = gridDim.x * 4;
  for (int i = wid; i < n; i += nw) {
    const float2 xv = ((const float2*)(X + (long)i * 128))[l];
    float sl = xv.x * al2.x + xv.y * al2.y;
    float sr = xv.x * ar2.x + xv.y * ar2.y;
    sl = wave_sum(sl);
    sr = wave_sum(sr);
    if (l == 0) {
      a_src[i] = sl;
      a_dst[i] = sr;
    }
  }
}

// ---------------------------------------------------------------------------
// CSR build (by dst, self-loops included via deg init = 1)
// init_deg also zeroes stat (for layer 0).
// ---------------------------------------------------------------------------
__global__ void init_deg(int* deg, int n, float* stat) {
  int i = blockIdx.x * 256 + threadIdx.x;
  if (i < n) deg[i] = 1;
  if (i < 256) stat[i] = 0.0f;
}
__global__ void hist_dst(const int* __restrict__ edst, int E, int* deg) {
  int e = blockIdx.x * 256 + threadIdx.x;
  if (e < E) atomicAdd(&deg[edst[e]], 1);
}
__global__ __launch_bounds__(256) void scan_partial(const int* __restrict__ deg,
                                                    int n, int* bsum) {
  __shared__ int r[256];
  int t = threadIdx.x;
  int g = blockIdx.x * 256 + t;
  r[t] = (g < n) ? deg[g] : 0;
  for (int o = 128; o; o >>= 1) {
    __syncthreads();
    if (t < o) r[t] += r[t + o];
  }
  if (t == 0) bsum[blockIdx.x] = r[0];
}
__global__ __launch_bounds__(256) void scan_bsums(int* bsum, int nb) {
  __shared__ int r[256];
  int t = threadIdx.x;
  int v = (t < nb) ? bsum[t] : 0;
  r[t] = v;
  for (int o = 1; o < 256; o <<= 1) {
    int x = 0;
    __syncthreads();
    if (t >= o) x = r[t - o];
    __syncthreads();
    r[t] += x;
  }
  if (t < nb) bsum[t] = r[t] - v;  // exclusive
}
__global__ __launch_bounds__(256) void scan_final(const int* __restrict__ deg,
                                                  int n,
                                                  const int* __restrict__ bsum,
                                                  int* offs, int* cursor) {
  __shared__ int r[256];
  int t = threadIdx.x;
  int g = blockIdx.x * 256 + t;
  int v = (g < n) ? deg[g] : 0;
  r[t] = v;
  for (int o = 1; o < 256; o <<= 1) {
    int x = 0;
    __syncthreads();
    if (t >= o) x = r[t - o];
    __syncthreads();
    r[t] += x;
  }
  int excl = bsum[blockIdx.x] + r[t] - v;
  if (g < n) {
    offs[g] = excl;
    cursor[g] = excl;
    if (g == n - 1) offs[n] = excl + v;
  }
}
__global__ void scatter_csr(const int* __restrict__ esrc,
                            const int* __restrict__ edst, int E, int n,
                            int* cursor, int* __restrict__ csr) {
  int g = blockIdx.x * 256 + threadIdx.x;
  if (g < E) {
    int d = edst[g];
    int p = atomicAdd(&cursor[d], 1);
    csr[p] = esrc[g];
  } else if (g < E + n) {
    int i = g - E;
    int p = atomicAdd(&cursor[i], 1);
    csr[p] = i;
  }
}

// ---------------------------------------------------------------------------
// Softmax aggregation, bf16 gather, 2 edges per wave-load (uint2 = 4ch).
// Wave owns node; wave-wide softmax as in R8; csr+alpha staged in LDS;
// halves combined via shfl_xor(32); lanes<32 write the 128-ch output.
// ---------------------------------------------------------------------------
__global__ __launch_bounds__(256) void aggregate_bf(
    const unsigned* __restrict__ Xb, const int* __restrict__ csr,
    const int* __restrict__ offs, const float* __restrict__ a_src,
    const float* __restrict__ a_dst, const float* __restrict__ bias,
    float* __restrict__ Y, unsigned* __restrict__ Yb,
    unsigned char* __restrict__ Y8, int n, int do_relu, int write_shadow,
    float* __restrict__ stat_zero) {
  if (blockIdx.x == 0 && threadIdx.x < 256) stat_zero[threadIdx.x] = 0.0f;
  __shared__ int sidx[4][128];
  __shared__ float salw[4][128];
  const uint2* __restrict__ Xb2 = (const uint2*)Xb;
  const int t = threadIdx.x;
  const int w = t >> 6, l = t & 63;
  const int h = l >> 5, j = l & 31;
  const int wid = blockIdx.x * 4 + w;
  const int nw = gridDim.x * 4;
  const float4 b4 = ((const float4*)bias)[j];
  for (int i = wid; i < n; i += nw) {
    const int beg = offs[i], end = offs[i + 1];
    const int deg = end - beg;
    const float adsti = a_dst[i];
    float acc[4] = {0.f, 0.f, 0.f, 0.f};
    if (deg <= 128) {
      int s0r = 0, s1r = 0;
      float a0 = -INFINITY, a1 = -INFINITY;
      if (l < deg) {
        s0r = csr[beg + l];
        float a = a_src[s0r] + adsti;
        a0 = (a > 0.0f ? a : 0.2f * a) * 0.1f;
      }
      if (64 + l < deg) {
        s1r = csr[beg + 64 + l];
        float a = a_src[s1r] + adsti;
        a1 = (a > 0.0f ? a : 0.2f * a) * 0.1f;
      }
      const float mx = wave_max(fmaxf(a0, a1));
      const float e0 = expf(a0 - mx);  // 0 for idle slots
      const float e1 = expf(a1 - mx);
      const float sm = wave_sum(e0 + e1);
      const float inv = 1.0f / (sm + 1e-16f);
      sidx[w][l] = s0r;
      salw[w][l] = e0 * inv;
      sidx[w][64 + l] = s1r;
      salw[w][64 + l] = e1 * inv;
      int b = 0;
      for (; b + 8 <= deg; b += 8) {
        int sx[4];
        float aw[4];
#pragma unroll
        for (int u = 0; u < 4; u++) {
          sx[u] = sidx[w][b + 2 * u + h];
          aw[u] = salw[w][b + 2 * u + h];
        }
        uint2 ua[4];
#pragma unroll
        for (int u = 0; u < 4; u++) ua[u] = Xb2[(long)sx[u] * 32 + j];
#pragma unroll
        for (int u = 0; u < 4; u++) {
          acc[0] = fmaf(aw[u], bflo(ua[u].x), acc[0]);
          acc[1] = fmaf(aw[u], bfhi(ua[u].x), acc[1]);
          acc[2] = fmaf(aw[u], bflo(ua[u].y), acc[2]);
          acc[3] = fmaf(aw[u], bfhi(ua[u].y), acc[3]);
        }
      }
      for (; b + 2 <= deg; b += 2) {
        const int sx = sidx[w][b + h];
        const float aw = salw[w][b + h];
        const uint2 ua = Xb2[(long)sx * 32 + j];
        acc[0] = fmaf(aw, bflo(ua.x), acc[0]);
        acc[1] = fmaf(aw, bfhi(ua.x), acc[1]);
        acc[2] = fmaf(aw, bflo(ua.y), acc[2]);
        acc[3] = fmaf(aw, bfhi(ua.y), acc[3]);
      }
      if (b < deg && h == 0) {  // odd remainder edge: half 0 only
        const int sx = sidx[w][b];
        const float aw = salw[w][b];
        const uint2 ua = Xb2[(long)sx * 32 + j];
        acc[0] = fmaf(aw, bflo(ua.x), acc[0]);
        acc[1] = fmaf(aw, bfhi(ua.x), acc[1]);
        acc[2] = fmaf(aw, bflo(ua.y), acc[2]);
        acc[3] = fmaf(aw, bfhi(ua.y), acc[3]);
      }
    } else {
      // 3-pass wave-wide softmax, then halves alternate edges
      float mx = -1e30f;
      for (int p = beg + l; p < end; p += 64) {
        float a = a_src[csr[p]] + adsti;
        a = (a > 0.0f ? a : 0.2f * a) * 0.1f;
        mx = fmaxf(mx, a);
      }
      mx = wave_max(mx);
      float sm = 0.0f;
      for (int p = beg + l; p < end; p += 64) {
        float a = a_src[csr[p]] + adsti;
        a = (a > 0.0f ? a : 0.2f * a) * 0.1f;
        sm += expf(a - mx);
      }
      sm = wave_sum(sm);
      const float inv = 1.0f / (sm + 1e-16f);
      for (int p = beg + h; p < end; p += 2) {
        const int sx = csr[p];
        float a = a_src[sx] + adsti;
        a = (a > 0.0f ? a : 0.2f * a) * 0.1f;
        const float aw = expf(a - mx) * inv;
        const uint2 ua = Xb2[(long)sx * 32 + j];
        acc[0] = fmaf(aw, bflo(ua.x), acc[0]);
        acc[1] = fmaf(aw, bfhi(ua.x), acc[1]);
        acc[2] = fmaf(aw, bflo(ua.y), acc[2]);
        acc[3] = fmaf(aw, bfhi(ua.y), acc[3]);
      }
    }
#pragma unroll
    for (int c = 0; c < 4; c++) acc[c] += __shfl_xor(acc[c], 32, 64);
    if (l < 32) {
      float4 o;
      o.x = acc[0] + b4.x;
      o.y = acc[1] + b4.y;
      o.z = acc[2] + b4.z;
      o.w = acc[3] + b4.w;
      if (do_relu) {
        o.x = fmaxf(o.x, 0.0f);
        o.y = fmaxf(o.y, 0.0f);
        o.z = fmaxf(o.z, 0.0f);
        o.w = fmaxf(o.w, 0.0f);
      }
      *(float4*)(Y + (long)i * 128 + 4 * j) = o;
      if (write_shadow) {
        uint2 pb;
        pb.x = packbf(o.x, o.y);
        pb.y = packbf(o.z, o.w);
        *(uint2*)(Yb + (long)i * 64 + 2 * j) = pb;
        unsigned w8 = __builtin_amdgcn_cvt_pk_fp8_f32(o.x, o.y, 0, false);
        w8 = __builtin_amdgcn_cvt_pk_fp8_f32(o.z, o.w, w8, true);
        ((unsigned*)Y8)[(long)i * 32 + j] = w8;
      }
    }
  }
}

// ---------------------------------------------------------------------------
extern "C" void kernel_launch(void* const* d_in, const int* in_sizes, int n_in,
                              void* d_out, int out_size, void* d_ws,
                              size_t ws_size, hipStream_t stream) {
  (void)n_in;
  (void)out_size;
  (void)ws_size;
  const float* x = (const float*)d_in[0];
  const int* ei = (const int*)d_in[1];
  const float* W0 = (const float*)d_in[2];
  const float* b0 = (const float*)d_in[3];
  const float* W2 = (const float*)d_in[4];
  const float* b2 = (const float*)d_in[5];
  const float* gsw[2] = {(const float*)d_in[6], (const float*)d_in[12]};
  const float* gsb[2] = {(const float*)d_in[7], (const float*)d_in[13]};
  const float* gdw[2] = {(const float*)d_in[8], (const float*)d_in[14]};
  const float* gdb[2] = {(const float*)d_in[9], (const float*)d_in[15]};
  const float* gtq[2] = {(const float*)d_in[10], (const float*)d_in[16]};
  const float* gbias[2] = {(const float*)d_in[11], (const float*)d_in[17]};

  const int N = in_sizes[0] / 128;
  const int E = in_sizes[1] / 2;
  const int* esrc = ei;
  const int* edst = ei + E;

  float* ws = (float*)d_ws;
  size_t o = 0;
  float* h0 = ws + o;
  o += (size_t)N * 128;
  float* h1 = ws + o;
  o += (size_t)N * 128;
  unsigned* h0b = (unsigned*)(ws + o);
  o += (size_t)N * 64;
  unsigned* h1b = (unsigned*)(ws + o);
  o += (size_t)N * 64;
  unsigned char* h0f8 = (unsigned char*)(ws + o);
  o += (size_t)N * 32;
  unsigned char* h1f8 = (unsigned char*)(ws + o);
  o += (size_t)N * 32;
  float* stat = ws + o;
  o += 256;
  float* a_src = ws + o;
  o += N;
  float* a_dst = ws + o;
  o += N;
  int* ip = (int*)(ws + o);
  int* deg = ip;
  ip += N;
  int* offs = ip;
  ip += N + 1;
  int* cursor = ip;
  ip += N;
  int* bsum = ip;
  ip += 256;
  int* csr = ip;
  ip += E + N;

  const int NB = (N + 255) / 256;  // 196 <= 256 required by scan_bsums

  // GEMM1: h0 = x @ W0^T + b0  (+ bf16 shadow h0b, fp8 shadow h0f8)
  gemm_bias<128, true><<<(N + 127) / 128, 256, 0, stream>>>(x, W0, b0, h0,
                                                            h0b, h0f8, N);

  // CSR build (shared by both convs); init_deg also zeroes stat
  init_deg<<<NB, 256, 0, stream>>>(deg, N, stat);
  hist_dst<<<(E + 255) / 256, 256, 0, stream>>>(edst, E, deg);
  scan_partial<<<NB, 256, 0, stream>>>(deg, N, bsum);
  scan_bsums<<<1, 256, 0, stream>>>(bsum, NB);
  scan_final<<<NB, 256, 0, stream>>>(deg, N, bsum, offs, cursor);
  scatter_csr<<<(E + N + 255) / 256, 256, 0, stream>>>(esrc, edst, E, N,
                                                       cursor, csr);

  for (int layer = 0; layer < 2; ++layer) {
    const float* Xf = layer ? h1 : h0;
    const unsigned* Xb = layer ? h1b : h0b;
    const unsigned char* X8 = layer ? h1f8 : h0f8;
    float* Yf = layer ? h0 : h1;
    unsigned* Yb = layer ? h0b : h1b;          // written only for layer 0
    unsigned char* Y8 = layer ? h0f8 : h1f8;   // written only for layer 0
    edge_stats_f8<<<2048, 256, 0, stream>>>(X8, csr, offs, N, stat);
    node_scores_att<<<1024, 256, 0, stream>>>(
        Xf, stat, gsw[layer], gsb[layer], gdw[layer], gdb[layer], gtq[layer],
        a_src, a_dst, N, (float)E);
    aggregate_bf<<<2048, 256, 0, stream>>>(
        Xb, csr, offs, a_src, a_dst, gbias[layer], Yf, Yb, Y8, N,
        layer == 0 ? 1 : 0, layer == 0 ? 1 : 0, stat);
  }

  // GEMM2: out = h0 @ W2^T + b2   (h0 holds conv2 output, fp32)
  gemm_bias<64, false><<<(N + 127) / 128, 256, 0, stream>>>(
      h0, W2, b2, (float*)d_out, nullptr, nullptr, N);
}